// Round 6
// baseline (3783.318 us; speedup 1.0000x reference)
//
#include <hip/hip_runtime.h>
#include <math.h>

// Problem constants
#define B_    8192
#define DIN_  1024
#define HID_  2048
#define LAT_  256
#define KC_   4096   // codebook size

using bfrag8 = __attribute__((ext_vector_type(8))) short;   // 8 bf16 (4 VGPR)
using facc4  = __attribute__((ext_vector_type(4))) float;   // MFMA C/D frag

__device__ __forceinline__ unsigned short f2bf(float f) {
    union { float f; unsigned int u; } c; c.f = f;
    unsigned int u = c.u;
    return (unsigned short)((u + 0x7FFFu + ((u >> 16) & 1u)) >> 16);   // RNE
}

// ---------------------------------------------------------------------------
// Encoder GEMM, fp64 accumulation, conflict-free strided tiling.
// BM = 16*RI, BN = 64. Thread (tx=tid&15, ty=tid>>4) owns rows {ty+16i},
// cols {tx+16j}. All ds_read/ds_write patterns are bank-balanced:
//   a[i] = As[kk][ty+16i]  -> 4 addrs/wave, 16-lane broadcast (free)
//   b[j] = Ws[kk][tx+16j]  -> 16 consecutive doubles (perfect tiling)
//   staging writes: row strides 130/66 doubles -> balanced (4 lanes/bank-pair)
// ---------------------------------------------------------------------------
template <int RI, bool GELU>
__global__ __launch_bounds__(256) void gemm_f64_strided(
    const float* __restrict__ A, const float* __restrict__ W,
    const float* __restrict__ bias, float* __restrict__ C,
    int M, int N, int K)
{
    __shared__ double As[16][RI * 16 + 2];
    __shared__ double Ws[16][66];

    const int tid = threadIdx.x;
    const int tx = tid & 15;         // col sub-slot / staging k
    const int ty = tid >> 4;         // row sub-slot
    const int m0 = blockIdx.x * (RI * 16);
    const int n0 = blockIdx.y * 64;
    const int wk = tid >> 6;         // staging: wave id -> k base
    const int wn = tid & 63;         // staging: n within W tile

    double acc[RI][4] = {};

    for (int k0 = 0; k0 < K; k0 += 16) {
        // stage A tile (BM x 16), cvt f32->f64 once here
#pragma unroll
        for (int i = 0; i < RI; ++i)
            As[tx][ty + 16 * i] = (double)A[(size_t)(m0 + ty + 16 * i) * K + k0 + tx];
        // stage W tile (16 x 64)
#pragma unroll
        for (int j = 0; j < 4; ++j)
            Ws[wk + 4 * j][wn] = (double)W[(size_t)(k0 + wk + 4 * j) * N + n0 + wn];
        __syncthreads();
#pragma unroll
        for (int kk = 0; kk < 16; ++kk) {
            double a[RI], b[4];
#pragma unroll
            for (int i = 0; i < RI; ++i) a[i] = As[kk][ty + 16 * i];
#pragma unroll
            for (int j = 0; j < 4; ++j) b[j] = Ws[kk][tx + 16 * j];
#pragma unroll
            for (int i = 0; i < RI; ++i)
#pragma unroll
                for (int j = 0; j < 4; ++j)
                    acc[i][j] = fma(a[i], b[j], acc[i][j]);
        }
        __syncthreads();
    }

    double bb[4];
#pragma unroll
    for (int j = 0; j < 4; ++j) bb[j] = (double)bias[n0 + tx + 16 * j];
#pragma unroll
    for (int i = 0; i < RI; ++i) {
        const int m = m0 + ty + 16 * i;
#pragma unroll
        for (int j = 0; j < 4; ++j) {
            double v = acc[i][j] + bb[j];
            if (GELU) v = 0.5 * v * (1.0 + erf(v * 0.70710678118654752440));
            C[(size_t)m * N + n0 + tx + 16 * j] = (float)v;
        }
    }
}

// ---------------------------------------------------------------------------
// Decoder GEMM: bf16 MFMA 16x16x32, 128x128 block tile, 4 waves (2x2 of 64x64)
// ---------------------------------------------------------------------------
template <int OUT_BF16>
__global__ __launch_bounds__(256) void gemm_mfma_bf16(
    const unsigned short* __restrict__ A,
    const unsigned short* __restrict__ WT,
    const float* __restrict__ bias,
    void* __restrict__ Cout,
    int M, int N, int K)
{
    __shared__ unsigned short As[128 * 64];
    __shared__ unsigned short Bs[128 * 64];

    const int tid  = threadIdx.x;
    const int wave = tid >> 6;
    const int lane = tid & 63;
    const int wm   = wave & 1;
    const int wn   = wave >> 1;
    const int quad = lane >> 4;
    const int ln   = lane & 15;
    const int m0 = blockIdx.x * 128;
    const int n0 = blockIdx.y * 128;

    facc4 acc[4][4] = {};

    for (int k0 = 0; k0 < K; k0 += 64) {
#pragma unroll
        for (int i = 0; i < 4; ++i) {
            const int idx = i * 256 + tid;
            const int row = idx >> 3;
            const int c8  = (idx & 7) * 8;
            *reinterpret_cast<bfrag8*>(&As[row * 64 + c8]) =
                *reinterpret_cast<const bfrag8*>(&A[(size_t)(m0 + row) * K + k0 + c8]);
            *reinterpret_cast<bfrag8*>(&Bs[row * 64 + c8]) =
                *reinterpret_cast<const bfrag8*>(&WT[(size_t)(n0 + row) * K + k0 + c8]);
        }
        __syncthreads();
#pragma unroll
        for (int ks = 0; ks < 64; ks += 32) {
            bfrag8 am[4], bn[4];
#pragma unroll
            for (int f = 0; f < 4; ++f) {
                am[f] = *reinterpret_cast<const bfrag8*>(
                    &As[(wm * 64 + f * 16 + ln) * 64 + ks + quad * 8]);
                bn[f] = *reinterpret_cast<const bfrag8*>(
                    &Bs[(wn * 64 + f * 16 + ln) * 64 + ks + quad * 8]);
            }
#pragma unroll
            for (int fm = 0; fm < 4; ++fm)
#pragma unroll
                for (int fn = 0; fn < 4; ++fn)
                    acc[fm][fn] = __builtin_amdgcn_mfma_f32_16x16x32_bf16(
                        am[fm], bn[fn], acc[fm][fn], 0, 0, 0);
        }
        __syncthreads();
    }

#pragma unroll
    for (int fn = 0; fn < 4; ++fn) {
        const int col = n0 + wn * 64 + fn * 16 + ln;
        const float bf = bias[col];
#pragma unroll
        for (int fm = 0; fm < 4; ++fm) {
            const int rbase = m0 + wm * 64 + fm * 16 + quad * 4;
#pragma unroll
            for (int r = 0; r < 4; ++r) {
                float v = acc[fm][fn][r] + bf;
                if (OUT_BF16) {
                    v = 0.5f * v * (1.0f + erff(v * 0.70710678118654752440f));
                    ((unsigned short*)Cout)[(size_t)(rbase + r) * N + col] = f2bf(v);
                } else {
                    ((float*)Cout)[(size_t)(rbase + r) * N + col] = v;
                }
            }
        }
    }
}

// ---------------------------------------------------------------------------
// Cast+transpose weights: W [K,N] fp32 -> WT [N,K] bf16
// ---------------------------------------------------------------------------
__global__ __launch_bounds__(256) void cast_transpose_w(
    const float* __restrict__ W, unsigned short* __restrict__ WT, int K, int N)
{
    __shared__ float t[32][33];
    const int k0 = blockIdx.x * 32;
    const int n0 = blockIdx.y * 32;
    const int x = threadIdx.x;
    const int y = threadIdx.y;
#pragma unroll
    for (int i = 0; i < 4; ++i)
        t[y + i * 8][x] = W[(size_t)(k0 + y + i * 8) * N + n0 + x];
    __syncthreads();
#pragma unroll
    for (int i = 0; i < 4; ++i)
        WT[(size_t)(n0 + y + i * 8) * K + k0 + x] = f2bf(t[x][y + i * 8]);
}

// ---------------------------------------------------------------------------
// Transpose embed [4096,256] -> embedT [256,4096] (fp32, for vq_argmin)
// ---------------------------------------------------------------------------
__global__ __launch_bounds__(256) void transpose_embed(
    const float* __restrict__ E, float* __restrict__ ET)
{
    __shared__ float t[32][33];
    const int c0 = blockIdx.x * 32;
    const int l0 = blockIdx.y * 32;
    const int x = threadIdx.x;
    const int y = threadIdx.y;
#pragma unroll
    for (int i = 0; i < 4; ++i)
        t[y + i * 8][x] = E[(size_t)(c0 + y + i * 8) * LAT_ + l0 + x];
    __syncthreads();
#pragma unroll
    for (int i = 0; i < 4; ++i)
        ET[(size_t)(l0 + y + i * 8) * KC_ + c0 + x] = t[x][y + i * 8];
}

// ---------------------------------------------------------------------------
// rowsq[r] = fp32( fp64 sum of X[r,:].^2 ), rows of width LAT_=256.
// ---------------------------------------------------------------------------
__global__ __launch_bounds__(64) void rowsq_kernel(
    const float* __restrict__ X, float* __restrict__ out,
    float* __restrict__ loss_slot)
{
    const int r = blockIdx.x;
    const float4 v = reinterpret_cast<const float4*>(X + (size_t)r * LAT_)[threadIdx.x];
    double s = (double)v.x * v.x + (double)v.y * v.y + (double)v.z * v.z + (double)v.w * v.w;
#pragma unroll
    for (int off = 32; off; off >>= 1) s += __shfl_down(s, off, 64);
    if (threadIdx.x == 0) {
        out[r] = (float)s;
        if (loss_slot != nullptr && r == 0) *loss_slot = 0.0f;
    }
}

// ---------------------------------------------------------------------------
// Fused distance + argmin (unchanged, known-good):
//   dist32 = fp32( fp32(zsq + esq) - fp32(2 * dot_f64) ), argmin first-index.
// ---------------------------------------------------------------------------
__global__ __launch_bounds__(256) void vq_argmin(
    const float* __restrict__ Z,     // [B,256]
    const float* __restrict__ ET,    // [256,4096]
    const float* __restrict__ esq,   // [4096] fp32
    const float* __restrict__ zsq,   // [B]    fp32
    float* __restrict__ pval, int* __restrict__ pidx)  // [B,8]
{
    __shared__ float Zs[16][68];
    __shared__ float Es[16][64];
    __shared__ float rv[64][16];
    __shared__ int   ri[64][16];

    const int tid = threadIdx.x;
    const int tx = tid & 15;
    const int ty = tid >> 4;
    const int m0 = blockIdx.x * 64;
    const int split = blockIdx.y;
    const int nbeg = split * (KC_ / 8);

    float zsqv[4];
#pragma unroll
    for (int i = 0; i < 4; ++i) zsqv[i] = zsq[m0 + ty * 4 + i];

    float bestv[4];
    int   besti[4];
#pragma unroll
    for (int i = 0; i < 4; ++i) { bestv[i] = 3.4e38f; besti[i] = 0; }

    for (int n0 = nbeg; n0 < nbeg + (KC_ / 8); n0 += 64) {
        double acc[4][4] = {};
        for (int k0 = 0; k0 < LAT_; k0 += 16) {
#pragma unroll
            for (int i = 0; i < 4; ++i) {
                int m = (tid >> 4) + i * 16;
                Zs[tid & 15][m] = Z[(size_t)(m0 + m) * LAT_ + k0 + (tid & 15)];
            }
#pragma unroll
            for (int i = 0; i < 4; ++i) {
                int k = (tid >> 6) + i * 4;
                Es[k][tid & 63] = ET[(size_t)(k0 + k) * KC_ + n0 + (tid & 63)];
            }
            __syncthreads();
#pragma unroll
            for (int kk = 0; kk < 16; ++kk) {
                const float4 a = *reinterpret_cast<const float4*>(&Zs[kk][ty * 4]);
                const float4 b = *reinterpret_cast<const float4*>(&Es[kk][tx * 4]);
                const double av[4] = {(double)a.x, (double)a.y, (double)a.z, (double)a.w};
                const double bv[4] = {(double)b.x, (double)b.y, (double)b.z, (double)b.w};
#pragma unroll
                for (int i = 0; i < 4; ++i)
#pragma unroll
                    for (int j = 0; j < 4; ++j)
                        acc[i][j] = fma(av[i], bv[j], acc[i][j]);
            }
            __syncthreads();
        }
#pragma unroll
        for (int j = 0; j < 4; ++j) {
            const int n = n0 + tx * 4 + j;
            const float es = esq[n];
#pragma unroll
            for (int i = 0; i < 4; ++i) {
                const float S   = zsqv[i] + es;
                const float t2m = (float)(2.0 * acc[i][j]);
                const float sc  = S - t2m;
                if (sc < bestv[i] || (sc == bestv[i] && n < besti[i])) {
                    bestv[i] = sc; besti[i] = n;
                }
            }
        }
    }
#pragma unroll
    for (int i = 0; i < 4; ++i) { rv[ty * 4 + i][tx] = bestv[i]; ri[ty * 4 + i][tx] = besti[i]; }
    __syncthreads();
    if (tid < 64) {
        float bv = rv[tid][0]; int bi = ri[tid][0];
#pragma unroll
        for (int t = 1; t < 16; ++t) {
            const float v = rv[tid][t]; const int ix = ri[tid][t];
            if (v < bv || (v == bv && ix < bi)) { bv = v; bi = ix; }
        }
        pval[(m0 + tid) * 8 + split] = bv;
        pidx[(m0 + tid) * 8 + split] = bi;
    }
}

// ---------------------------------------------------------------------------
// Finalize: reduce 8 partials -> index (float), gather z_q (bf16), loss atomics
// ---------------------------------------------------------------------------
__global__ __launch_bounds__(64) void vq_finalize(
    const float* __restrict__ pval, const int* __restrict__ pidx,
    const float* __restrict__ Z, const float* __restrict__ E,
    unsigned short* __restrict__ zqb, float* __restrict__ out_idx,
    float* __restrict__ loss_slot)
{
    const int row = blockIdx.x;
    __shared__ int sidx;
    if (threadIdx.x == 0) {
        float bv = pval[row * 8]; int bi = pidx[row * 8];
#pragma unroll
        for (int s = 1; s < 8; ++s) {
            const float v = pval[row * 8 + s]; const int ix = pidx[row * 8 + s];
            if (v < bv || (v == bv && ix < bi)) { bv = v; bi = ix; }
        }
        sidx = bi;
        out_idx[row] = (float)bi;
    }
    __syncthreads();
    const int idx = sidx;
    const float4 e = reinterpret_cast<const float4*>(E + (size_t)idx * LAT_)[threadIdx.x];
    const float4 z = reinterpret_cast<const float4*>(Z + (size_t)row * LAT_)[threadIdx.x];
    ushort4 q; q.x = f2bf(e.x); q.y = f2bf(e.y); q.z = f2bf(e.z); q.w = f2bf(e.w);
    reinterpret_cast<ushort4*>(zqb + (size_t)row * LAT_)[threadIdx.x] = q;
    const float dx = z.x - e.x, dy = z.y - e.y, dz = z.z - e.z, dw = z.w - e.w;
    float s = dx * dx + dy * dy + dz * dz + dw * dw;
#pragma unroll
    for (int off = 32; off; off >>= 1) s += __shfl_down(s, off, 64);
    if (threadIdx.x == 0)
        atomicAdd(loss_slot, s * (1.25f / ((float)B_ * (float)LAT_)));
}

// ---------------------------------------------------------------------------
extern "C" void kernel_launch(void* const* d_in, const int* in_sizes, int n_in,
                              void* d_out, int out_size, void* d_ws, size_t ws_size,
                              hipStream_t stream)
{
    const float* x   = (const float*)d_in[0];
    const float* W1  = (const float*)d_in[1];
    const float* b1  = (const float*)d_in[2];
    const float* W2  = (const float*)d_in[3];
    const float* b2  = (const float*)d_in[4];
    const float* W3  = (const float*)d_in[5];
    const float* b3  = (const float*)d_in[6];
    const float* emb = (const float*)d_in[7];
    const float* D1  = (const float*)d_in[8];
    const float* d1  = (const float*)d_in[9];
    const float* D2  = (const float*)d_in[10];
    const float* d2  = (const float*)d_in[11];
    const float* D3  = (const float*)d_in[12];
    const float* d3  = (const float*)d_in[13];
    float* out = (float*)d_out;

    char* ws = (char*)d_ws;
    float* h1   = (float*)(ws);
    float* h2   = (float*)(ws + 67108864);
    float* ze   = (float*)(ws + 134217728);
    unsigned short* zqb = (unsigned short*)(ws + 142606336);
    float* embT = (float*)(ws + 146800640);
    float* esq  = (float*)(ws + 150994944);
    float* zsq  = (float*)(ws + 151011328);
    float* pval = (float*)(ws + 151044096);
    int*   pidx = (int*)  (ws + 151306240);
    unsigned short* g1b = (unsigned short*)(ws);              // over h1 (dead)
    unsigned short* g2b = (unsigned short*)(ws + 33554432);
    unsigned short* wt1 = (unsigned short*)(ws + 67108864);   // over h2 (dead)
    unsigned short* wt2 = (unsigned short*)(ws + 68157440);
    unsigned short* wt3 = (unsigned short*)(ws + 76546048);

    float* loss_slot = out + (size_t)B_ * DIN_;     // d_out[8388608]
    float* out_idx   = loss_slot + 1;               // d_out[8388609..]

    // codebook prep (esq kernel also zeroes loss slot)
    rowsq_kernel<<<KC_, 64, 0, stream>>>(emb, esq, loss_slot);
    transpose_embed<<<dim3(KC_ / 32, LAT_ / 32), dim3(32, 8), 0, stream>>>(emb, embT);

    // encoder — fp64 accumulation, conflict-free strided tiling
    gemm_f64_strided<8, true ><<<dim3(B_ / 128, HID_ / 64), 256, 0, stream>>>(x,  W1, b1, h1, B_, HID_, DIN_);
    gemm_f64_strided<8, true ><<<dim3(B_ / 128, HID_ / 64), 256, 0, stream>>>(h1, W2, b2, h2, B_, HID_, HID_);
    gemm_f64_strided<4, false><<<dim3(B_ /  64, LAT_ / 64), 256, 0, stream>>>(h2, W3, b3, ze, B_, LAT_, HID_);

    // z row norms
    rowsq_kernel<<<B_, 64, 0, stream>>>(ze, zsq, nullptr);

    // decoder weight prep (after enc3: wt* overlay h2)
    cast_transpose_w<<<dim3(LAT_ / 32, HID_ / 32), dim3(32, 8), 0, stream>>>(D1, wt1, LAT_, HID_);
    cast_transpose_w<<<dim3(HID_ / 32, HID_ / 32), dim3(32, 8), 0, stream>>>(D2, wt2, HID_, HID_);
    cast_transpose_w<<<dim3(HID_ / 32, DIN_ / 32), dim3(32, 8), 0, stream>>>(D3, wt3, HID_, DIN_);

    // VQ — numpy-fp32-mimicking scores, first-index tie-break
    vq_argmin<<<dim3(B_ / 64, 8), 256, 0, stream>>>(ze, embT, esq, zsq, pval, pidx);
    vq_finalize<<<B_, 64, 0, stream>>>(pval, pidx, ze, emb, zqb, out_idx, loss_slot);

    // decoder — bf16 MFMA (numerically free vs threshold)
    gemm_mfma_bf16<1><<<dim3(B_ / 128, HID_ / 128), 256, 0, stream>>>(zqb, wt1, d1, (void*)g1b, B_, HID_, LAT_);
    gemm_mfma_bf16<1><<<dim3(B_ / 128, HID_ / 128), 256, 0, stream>>>(g1b, wt2, d2, (void*)g2b, B_, HID_, HID_);
    gemm_mfma_bf16<0><<<dim3(B_ / 128, DIN_ / 128), 256, 0, stream>>>(g2b, wt3, d3, (void*)out, B_, DIN_, HID_);
}